// Round 9
// baseline (808.715 us; speedup 1.0000x reference)
//
#include <hip/hip_runtime.h>
#include <math.h>

// ---------------- types ----------------
typedef __bf16 bf16x8 __attribute__((ext_vector_type(8)));
typedef float  floatx4 __attribute__((ext_vector_type(4)));

__device__ inline float bf_lo(unsigned u){ return __uint_as_float(u << 16); }
__device__ inline float bf_hi(unsigned u){ return __uint_as_float(u & 0xffff0000u); }
__device__ inline unsigned short f2bf_u(float f){
    unsigned u = __float_as_uint(f);
    return (unsigned short)((u + 0x7fffu + ((u >> 16) & 1u)) >> 16);   // RNE
}
__device__ inline unsigned pack2(float a, float b){
    return (unsigned)f2bf_u(a) | ((unsigned)f2bf_u(b) << 16);
}
__device__ inline float gelu_f(float v){
    return 0.5f * v * (1.f + erff(v * 0.70710678118654752f));
}
__device__ inline void gload_lds16(const void* g, void* l){
    __builtin_amdgcn_global_load_lds(
        (const __attribute__((address_space(1))) unsigned int*)g,
        (__attribute__((address_space(3))) unsigned int*)l, 16, 0, 0);
}

// ---------------- utility ----------------
__global__ void zero_k(int* __restrict__ p, int n){
    int i = blockIdx.x * 256 + threadIdx.x;
    if (i < n) p[i] = 0;
}

__global__ void xcast_k(const float* __restrict__ x, unsigned short* __restrict__ xb, long n8){
    long i = (long)blockIdx.x * 256 + threadIdx.x;
    if (i < n8){
        const float4* p = (const float4*)(x + i * 8);
        float4 a = p[0], b = p[1];
        uint4 o;
        o.x = pack2(a.x, a.y); o.y = pack2(a.z, a.w);
        o.z = pack2(b.x, b.y); o.w = pack2(b.z, b.w);
        *(uint4*)(xb + i * 8) = o;
    }
}

// Wt[n*ostride + ooffs + k] = W[k][n], bf16
__global__ void wprep_k(const float* __restrict__ W, unsigned short* __restrict__ Wt,
                        int K, int Ncols, int ostride, int ooffs){
    int idx = blockIdx.x * 256 + threadIdx.x;
    if (idx < K * Ncols){
        int k = idx / Ncols, n = idx - k * Ncols;
        Wt[(size_t)n * ostride + ooffs + k] = f2bf_u(W[idx]);
    }
}

// ---------------- BN1 folding helpers ----------------
__global__ void mkbn_k(const float* __restrict__ gsum, const float* __restrict__ gsq,
                       const float* __restrict__ gamma, const float* __restrict__ beta,
                       const float* __restrict__ brel,
                       float* __restrict__ scv, float* __restrict__ shv,
                       float* __restrict__ bias2, float* __restrict__ rvec,
                       int C_, float invN){
    int c = blockIdx.x * 256 + threadIdx.x;
    if (c < C_){
        float mean = gsum[c] * invN;
        float var  = gsq[c] * invN - mean * mean;
        float sc   = gamma[c] * rsqrtf(var + 1e-5f);
        scv[c] = sc;
        shv[c] = beta[c] - mean * sc;
        bias2[c] = brel[c];
        rvec[c]  = 0.f;
    }
}

// wt_rr[n][k'] *= sc[k' & 255]
__global__ void wscale_k(unsigned short* __restrict__ wt, const float* __restrict__ scv, int total){
    int i = blockIdx.x * 256 + threadIdx.x;
    if (i < total){
        float v = __uint_as_float(((unsigned)wt[i]) << 16);
        wt[i] = f2bf_u(v * scv[i & 255]);
    }
}

// bias2[m] += sh@Wroot[:,m];  rvec[m] += sh@Wrel[:,m]  (8 blocks, k-split)
__global__ void biasrr_k(const float* __restrict__ Wrel, const float* __restrict__ Wroot,
                         const float* __restrict__ shv,
                         float* __restrict__ bias2, float* __restrict__ rvec){
    int m = threadIdx.x;
    int k0 = blockIdx.x * 32;
    float b2 = 0.f, rv = 0.f;
    for (int k = k0; k < k0 + 32; ++k){
        float s = shv[k];
        rv = fmaf(s, Wrel[k * 256 + m], rv);
        b2 = fmaf(s, Wroot[k * 256 + m], b2);
    }
    atomicAdd(&bias2[m], b2);
    atomicAdd(&rvec[m],  rv);
}

// ---------------- bucketed CSR build ----------------
#define RBSH 9
#define RB   512
#define PCH  8192

__global__ __launch_bounds__(256)
void bhist_k(const int* __restrict__ dst, int* __restrict__ bcnt, int E){
    __shared__ int h[256];
    for (int i = threadIdx.x; i < 256; i += 256) h[i] = 0;
    __syncthreads();
    for (long i = (long)blockIdx.x * 256 + threadIdx.x; i < E; i += (long)gridDim.x * 256)
        atomicAdd(&h[dst[i] >> RBSH], 1);
    __syncthreads();
    int v = h[threadIdx.x];
    if (v) atomicAdd(&bcnt[threadIdx.x * 16], v);
}

__global__ void bscan_k(const int* __restrict__ bcnt, int* __restrict__ bbase,
                        int* __restrict__ bcur, int nbuk, int E){
    __shared__ int s[256];
    const int t = threadIdx.x;
    int v = (t < nbuk) ? bcnt[t * 16] : 0;
    s[t] = v; __syncthreads();
    for (int d = 1; d < 256; d <<= 1){
        int tt = (t >= d) ? s[t - d] : 0;
        __syncthreads();
        s[t] += tt;
        __syncthreads();
    }
    int excl = s[t] - v;
    if (t < nbuk){ bbase[t] = excl; bcur[t * 16] = excl; }
    if (t == 0) bbase[nbuk] = E;
}

__global__ __launch_bounds__(512)
void bpart_k(const int* __restrict__ src, const int* __restrict__ dst,
             int* __restrict__ bcur, int2* __restrict__ pairs, int E){
    __shared__ int h[256];
    __shared__ int s[256];
    __shared__ int cur[256];
    const int t = threadIdx.x;
    const int base = blockIdx.x * PCH;
    const int cnt = min(PCH, E - base);
    if (t < 256) h[t] = 0;
    __syncthreads();
    for (int i = t; i < cnt; i += 512)
        atomicAdd(&h[dst[base + i] >> RBSH], 1);
    __syncthreads();
    if (t < 256) s[t] = h[t];
    __syncthreads();
    for (int d = 1; d < 256; d <<= 1){
        int tt = 0;
        if (t < 256 && t >= d) tt = s[t - d];
        __syncthreads();
        if (t < 256) s[t] += tt;
        __syncthreads();
    }
    if (t < 256){
        int myc = h[t];
        int g = 0;
        if (myc) g = atomicAdd(&bcur[t * 16], myc);
        cur[t] = g;
    }
    __syncthreads();
    for (int i = t; i < cnt; i += 512){
        int d = dst[base + i];
        int b = d >> RBSH;
        int r = atomicAdd(&cur[b], 1);
        pairs[r] = make_int2(src[base + i], d);
    }
}

__global__ __launch_bounds__(1024)
void bbuild_k(const int2* __restrict__ pairs, const int* __restrict__ bbase,
              int* __restrict__ offsets, int* __restrict__ esrc, int N, int E){
    __shared__ int h[RB];
    __shared__ int s[RB];
    const int b = blockIdx.x;
    const int t = threadIdx.x;
    const int p0 = bbase[b], p1 = bbase[b + 1];
    if (t < RB) h[t] = 0;
    __syncthreads();
    for (int i = p0 + t; i < p1; i += 1024)
        atomicAdd(&h[pairs[i].y & (RB - 1)], 1);
    __syncthreads();
    int v = 0;
    if (t < RB){ v = h[t]; s[t] = v; }
    __syncthreads();
    for (int d = 1; d < RB; d <<= 1){
        int tt = 0;
        if (t < RB && t >= d) tt = s[t - d];
        __syncthreads();
        if (t < RB) s[t] += tt;
        __syncthreads();
    }
    if (t < RB){
        int node = (b << RBSH) + t;
        int excl = p0 + s[t] - v;
        if (node < N) offsets[node] = excl;
        h[t] = excl;
    }
    __syncthreads();
    for (int i = p0 + t; i < p1; i += 1024){
        int2 pr = pairs[i];
        int r = atomicAdd(&h[pr.y & (RB - 1)], 1);
        esrc[r] = pr.x;
    }
    if (b == 0 && t == 0) offsets[N] = E;
}

// ---------------- aggregation: agg(raw h1) into AG[:,0:256]; h1raw = AG+256, stride 512 ----------------
__global__ __launch_bounds__(256)
void agg_k(const unsigned short* __restrict__ hbn, const int* __restrict__ offsets,
           const int* __restrict__ esrc, unsigned short* __restrict__ aggout, int N){
    const int lane = threadIdx.x & 63;
    const int node = blockIdx.x * 4 + (threadIdx.x >> 6);
    if (node >= N) return;
    const int off  = offsets[node];
    const int end  = offsets[node + 1];
    const int half = lane >> 5;
    const int l32  = lane & 31;
    float a[8];
#pragma unroll
    for (int j = 0; j < 8; ++j) a[j] = 0.f;
    const unsigned short* hb = hbn + l32 * 8;
    for (int c = off; c < end; c += 64){
        const int e = c + lane;
        int sl = (e < end) ? esrc[e] : 0;
        const int cnt = min(64, end - c);
        for (int j = 0; j < cnt; j += 16){
            int   s[8];
            float m[8];
            uint4 u[8];
#pragma unroll
            for (int k = 0; k < 8; ++k){
                const int idx = j + 2 * k + half;
                s[k] = __shfl(sl, idx);
                m[k] = (idx < cnt) ? 1.f : 0.f;
            }
#pragma unroll
            for (int k = 0; k < 8; ++k)
                u[k] = *(const uint4*)(hb + (size_t)s[k] * 512);
#pragma unroll
            for (int k = 0; k < 8; ++k){
                a[0] = fmaf(m[k], bf_lo(u[k].x), a[0]);
                a[1] = fmaf(m[k], bf_hi(u[k].x), a[1]);
                a[2] = fmaf(m[k], bf_lo(u[k].y), a[2]);
                a[3] = fmaf(m[k], bf_hi(u[k].y), a[3]);
                a[4] = fmaf(m[k], bf_lo(u[k].z), a[4]);
                a[5] = fmaf(m[k], bf_hi(u[k].z), a[5]);
                a[6] = fmaf(m[k], bf_lo(u[k].w), a[6]);
                a[7] = fmaf(m[k], bf_hi(u[k].w), a[7]);
            }
        }
    }
#pragma unroll
    for (int j = 0; j < 8; ++j)
        a[j] += __shfl_xor(a[j], 32);
    if (half == 0){
        uint4 o;
        o.x = pack2(a[0], a[1]); o.y = pack2(a[2], a[3]);
        o.z = pack2(a[4], a[5]); o.w = pack2(a[6], a[7]);
        *(uint4*)(aggout + (size_t)node * 512 + l32 * 8) = o;
    }
}

// ---------------- GEMM (2-phase double-buffered LDS + XCD-chunked grid + deg rank-1) ----------------
// stage(kt+1) issued BEFORE compute(kt): loads fly under ds_read+MFMA, one
// vmcnt(0)+barrier per K-step. LDS 48KB -> 3 blocks/CU.
template<int K, bool GELU_OUT, bool DEGBIAS>
__global__ __launch_bounds__(256)
void gemm3_k(const unsigned short* __restrict__ A, const unsigned short* __restrict__ Bt,
             const float* __restrict__ bias, unsigned short* __restrict__ Cp,
             long M, int NY, int ostride, int ooffs,
             const int* __restrict__ offs, const float* __restrict__ rvec){
    __shared__ unsigned short Xs[2][128 * 64];   // [buf][row][k]
    __shared__ unsigned short Ws[2][64 * 64];    // [buf][col][k]
    const int t    = threadIdx.x;
    const int lane = t & 63;
    const int w    = t >> 6;
    const int r16  = lane & 15;
    const int q4   = lane >> 4;

    // bijective XCD remap + y-fastest decomposition
    const int nwg  = gridDim.x;
    const int orig = blockIdx.x;
    const int qq   = nwg >> 3, rr = nwg & 7;
    const int xcd  = orig & 7, kk = orig >> 3;
    const int wgid = (xcd < rr ? xcd * (qq + 1) : rr * (qq + 1) + (xcd - rr) * qq) + kk;
    const int xb   = wgid / NY;
    const int yb   = wgid - xb * NY;
    const long mbase = (long)xb * 128;
    const int  cb    = yb * 64;

    floatx4 acc[4][2];
#pragma unroll
    for (int ai = 0; ai < 4; ++ai)
#pragma unroll
        for (int bi = 0; bi < 2; ++bi) acc[ai][bi] = (floatx4)0.f;

    const int lrow = w * 8 + (lane >> 3);
    const int lk   = (lane & 7) * 8;
    const unsigned short* ga = A  + (size_t)(mbase + lrow) * K + lk;
    const unsigned short* gb = Bt + (size_t)(cb + lrow) * K + lk;
    const int lddst = w * 512 + lane * 8;

    // prologue: stage kt=0 into buf 0
#pragma unroll
    for (int i = 0; i < 4; ++i)
        gload_lds16(ga + (size_t)i * 32 * K, Xs[0] + lddst + i * 2048);
#pragma unroll
    for (int j = 0; j < 2; ++j)
        gload_lds16(gb + (size_t)j * 32 * K, Ws[0] + lddst + j * 2048);
    asm volatile("s_waitcnt vmcnt(0)" ::: "memory");
    __syncthreads();

    int cur = 0;
    for (int kt = 0; kt < K; kt += 64){
        // stage next tile into other buffer (issued before compute)
        if (kt + 64 < K){
#pragma unroll
            for (int i = 0; i < 4; ++i)
                gload_lds16(ga + (size_t)i * 32 * K + kt + 64, Xs[cur ^ 1] + lddst + i * 2048);
#pragma unroll
            for (int j = 0; j < 2; ++j)
                gload_lds16(gb + (size_t)j * 32 * K + kt + 64, Ws[cur ^ 1] + lddst + j * 2048);
        }
        // compute current buffer
#pragma unroll
        for (int kc = 0; kc < 64; kc += 32){
            bf16x8 wf[4], xf[2];
#pragma unroll
            for (int ai = 0; ai < 4; ++ai)
                wf[ai] = *(const bf16x8*)(Ws[cur] + (ai * 16 + r16) * 64 + kc + q4 * 8);
#pragma unroll
            for (int bi = 0; bi < 2; ++bi)
                xf[bi] = *(const bf16x8*)(Xs[cur] + (w * 32 + bi * 16 + r16) * 64 + kc + q4 * 8);
#pragma unroll
            for (int ai = 0; ai < 4; ++ai)
#pragma unroll
                for (int bi = 0; bi < 2; ++bi)
                    acc[ai][bi] = __builtin_amdgcn_mfma_f32_16x16x32_bf16(
                        wf[ai], xf[bi], acc[ai][bi], 0, 0, 0);
        }
        asm volatile("s_waitcnt vmcnt(0)" ::: "memory");
        __syncthreads();
        cur ^= 1;
    }

    float4 bv[4];
#pragma unroll
    for (int ai = 0; ai < 4; ++ai)
        bv[ai] = *(const float4*)(bias + cb + ai * 16 + q4 * 4);
    float4 rv[4];
    if constexpr (DEGBIAS){
#pragma unroll
        for (int ai = 0; ai < 4; ++ai)
            rv[ai] = *(const float4*)(rvec + cb + ai * 16 + q4 * 4);
    }
#pragma unroll
    for (int bi = 0; bi < 2; ++bi){
        long node = mbase + w * 32 + bi * 16 + r16;
        if (node < M){
            float degf = 0.f;
            if constexpr (DEGBIAS) degf = (float)(offs[node + 1] - offs[node]);
            unsigned short* cp = Cp + (size_t)node * ostride + ooffs + cb;
#pragma unroll
            for (int ai = 0; ai < 4; ++ai){
                float v0 = acc[ai][bi][0] + bv[ai].x;
                float v1 = acc[ai][bi][1] + bv[ai].y;
                float v2 = acc[ai][bi][2] + bv[ai].z;
                float v3 = acc[ai][bi][3] + bv[ai].w;
                if constexpr (DEGBIAS){
                    v0 = fmaf(degf, rv[ai].x, v0);
                    v1 = fmaf(degf, rv[ai].y, v1);
                    v2 = fmaf(degf, rv[ai].z, v2);
                    v3 = fmaf(degf, rv[ai].w, v3);
                }
                if constexpr (GELU_OUT){
                    v0 = gelu_f(v0); v1 = gelu_f(v1); v2 = gelu_f(v2); v3 = gelu_f(v3);
                }
                uint2 o; o.x = pack2(v0, v1); o.y = pack2(v2, v3);
                *(uint2*)(cp + ai * 16 + q4 * 4) = o;
            }
        }
    }
}

// ---------------- column stats (strided-input capable) ----------------
template<int NCOLS>
__global__ void colstats_k(const unsigned short* __restrict__ in,
                           float* __restrict__ gsum, float* __restrict__ gsq,
                           long nrows, int ostride, int ooffs){
    constexpr int TPR  = NCOLS / 8;
    constexpr int BDIM = (NCOLS == 192) ? 192 : 256;
    constexpr int ROWS = BDIM / TPR;
    __shared__ float sS[ROWS * NCOLS], sQ[ROWS * NCOLS];
    const int t  = threadIdx.x;
    const int c8 = (t % TPR) * 8;
    const int r  = t / TPR;
    float s[8], q[8];
#pragma unroll
    for (int j = 0; j < 8; ++j){ s[j] = 0.f; q[j] = 0.f; }
    for (long row = (long)blockIdx.x * ROWS + r; row < nrows; row += (long)gridDim.x * ROWS){
        uint4 u = *(const uint4*)(in + row * ostride + ooffs + c8);
        float v[8];
        v[0] = bf_lo(u.x); v[1] = bf_hi(u.x); v[2] = bf_lo(u.y); v[3] = bf_hi(u.y);
        v[4] = bf_lo(u.z); v[5] = bf_hi(u.z); v[6] = bf_lo(u.w); v[7] = bf_hi(u.w);
#pragma unroll
        for (int j = 0; j < 8; ++j){ s[j] += v[j]; q[j] += v[j] * v[j]; }
    }
#pragma unroll
    for (int j = 0; j < 8; ++j){ sS[r * NCOLS + c8 + j] = s[j]; sQ[r * NCOLS + c8 + j] = q[j]; }
    __syncthreads();
    for (int c = t; c < NCOLS; c += BDIM){
        float as = 0.f, aq = 0.f;
#pragma unroll
        for (int rr = 0; rr < ROWS; ++rr){ as += sS[rr * NCOLS + c]; aq += sQ[rr * NCOLS + c]; }
        atomicAdd(&gsum[c], as);
        atomicAdd(&gsq[c],  aq);
    }
}

// ---------------- BN apply (+gelu, +residual, strided out, fp32/bf16 out) ----------------
template<int NCOLS, bool GELU_OUT, bool RES, bool RES_F32, bool OUT_F32>
__global__ __launch_bounds__(256)
void bn_apply_k(const unsigned short* __restrict__ in, void* __restrict__ outv,
                const void* __restrict__ resv,
                const float* __restrict__ gsum, const float* __restrict__ gsq,
                const float* __restrict__ gamma, const float* __restrict__ beta,
                long nrows, int ostride, int ooffs, float invN){
    __shared__ float s_scale[NCOLS], s_shift[NCOLS];
    for (int c = threadIdx.x; c < NCOLS; c += 256){
        float mean = gsum[c] * invN;
        float var  = gsq[c] * invN - mean * mean;
        float sc   = gamma[c] * rsqrtf(var + 1e-5f);
        s_scale[c] = sc;
        s_shift[c] = beta[c] - mean * sc;
    }
    __syncthreads();
    long i8 = ((long)blockIdx.x * 256 + threadIdx.x) * 8;
    if (i8 >= nrows * (long)NCOLS) return;
    long row  = i8 / NCOLS;
    int  col0 = (int)(i8 - row * NCOLS);
    uint4 u = *(const uint4*)(in + i8);
    float v[8];
    v[0] = bf_lo(u.x); v[1] = bf_hi(u.x); v[2] = bf_lo(u.y); v[3] = bf_hi(u.y);
    v[4] = bf_lo(u.z); v[5] = bf_hi(u.z); v[6] = bf_lo(u.w); v[7] = bf_hi(u.w);
#pragma unroll
    for (int j = 0; j < 8; ++j){
        v[j] = v[j] * s_scale[col0 + j] + s_shift[col0 + j];
        if constexpr (GELU_OUT) v[j] = gelu_f(v[j]);
    }
    if constexpr (RES){
        if constexpr (RES_F32){
            const float4* rp = (const float4*)((const float*)resv + i8);
            float4 r0 = rp[0], r1 = rp[1];
            v[0] += r0.x; v[1] += r0.y; v[2] += r0.z; v[3] += r0.w;
            v[4] += r1.x; v[5] += r1.y; v[6] += r1.z; v[7] += r1.w;
        } else {
            uint4 r = *(const uint4*)((const unsigned short*)resv + i8);
            v[0] += bf_lo(r.x); v[1] += bf_hi(r.x); v[2] += bf_lo(r.y); v[3] += bf_hi(r.y);
            v[4] += bf_lo(r.z); v[5] += bf_hi(r.z); v[6] += bf_lo(r.w); v[7] += bf_hi(r.w);
        }
    }
    long opos = row * ostride + ooffs + col0;
    if constexpr (OUT_F32){
        float4* op = (float4*)((float*)outv + opos);
        op[0] = make_float4(v[0], v[1], v[2], v[3]);
        op[1] = make_float4(v[4], v[5], v[6], v[7]);
    } else {
        uint4 o;
        o.x = pack2(v[0], v[1]); o.y = pack2(v[2], v[3]);
        o.z = pack2(v[4], v[5]); o.w = pack2(v[6], v[7]);
        *(uint4*)((unsigned short*)outv + opos) = o;
    }
}

// ---------------- host ----------------
extern "C" void kernel_launch(void* const* d_in, const int* in_sizes, int n_in,
                              void* d_out, int out_size, void* d_ws, size_t ws_size,
                              hipStream_t stream){
    const int C = 192, GH = 256, FH = 512;
    const float* x    = (const float*)d_in[0];
    const int*   ei   = (const int*)d_in[1];
    const float* Wg1  = (const float*)d_in[2];
    const float* bg1  = (const float*)d_in[3];
    const float* gg1  = (const float*)d_in[4];
    const float* beg1 = (const float*)d_in[5];
    const float* Wrel = (const float*)d_in[6];
    const float* brel = (const float*)d_in[7];
    const float* Wroot= (const float*)d_in[8];
    const float* Wg2  = (const float*)d_in[9];
    const float* bg2  = (const float*)d_in[10];
    const float* gg2  = (const float*)d_in[11];
    const float* beg2 = (const float*)d_in[12];
    const float* Wf1  = (const float*)d_in[13];
    const float* bf1  = (const float*)d_in[14];
    const float* gf1  = (const float*)d_in[15];
    const float* bef1 = (const float*)d_in[16];
    const float* Wf2  = (const float*)d_in[17];
    const float* bf2  = (const float*)d_in[18];
    const float* gf2  = (const float*)d_in[19];
    const float* bef2 = (const float*)d_in[20];

    const int N = in_sizes[0] / C;
    const int E = in_sizes[1] / 2;
    const int* e_src = ei;
    const int* e_dst = ei + E;

    char* wp = (char*)d_ws;
    auto carve = [&](size_t bytes) -> void* {
        void* p = (void*)wp; wp += (bytes + 255) & ~(size_t)255; return p;
    };
    unsigned short* wt_g1 = (unsigned short*)carve((size_t)GH * C * 2);
    unsigned short* wt_rr = (unsigned short*)carve((size_t)GH * 512 * 2);
    unsigned short* wt_g2 = (unsigned short*)carve((size_t)C * GH * 2);
    unsigned short* wt_f1 = (unsigned short*)carve((size_t)FH * C * 2);
    unsigned short* wt_f2 = (unsigned short*)carve((size_t)C * FH * 2);
    float* stats = (float*)carve(2 * (size_t)(GH + C + FH + C) * 4);
    float* sum1 = stats;        float* sq1 = sum1 + GH;
    float* sum2 = sq1 + GH;     float* sq2 = sum2 + C;
    float* sum3 = sq2 + C;      float* sq3 = sum3 + FH;
    float* sum4 = sq3 + FH;     float* sq4 = sum4 + C;
    float* scv   = (float*)carve(256 * 4);
    float* shv   = (float*)carve(256 * 4);
    float* bias2 = (float*)carve(256 * 4);
    float* rvec  = (float*)carve(256 * 4);
    // buf0: pairs (build) -> x_bf[N,192] -> g[N,256] -> f1/g2[N,512]
    unsigned short* buf0  = (unsigned short*)carve((size_t)N * 512 * 2);
    // bufAG: AG=[agg|h1raw] stride 512 -> h2/x2[N,192]@0, h4[N,192]@N*192
    unsigned short* bufAG = (unsigned short*)carve((size_t)N * 512 * 2);
    int* offsets = (int*)carve((size_t)(N + 1) * 4);
    int* esrc    = (int*)carve((size_t)E * 4);
    int* bcnt    = (int*)carve((size_t)256 * 16 * 4);
    int* bbase   = (int*)carve((size_t)257 * 4);
    int* bcur    = (int*)carve((size_t)256 * 16 * 4);
    int2* pairs = (int2*)buf0;
    unsigned short* x_bf = buf0;
    unsigned short* g    = buf0;
    unsigned short* f1   = buf0;
    unsigned short* AG   = bufAG;
    unsigned short* h2   = bufAG;
    unsigned short* h4   = bufAG + (size_t)N * C;
    (void)ws_size; (void)n_in; (void)out_size;

    const float invN = 1.0f / (float)N;
    const int GB = (N + 127) / 128;
    const int nbuk = (N + RB - 1) >> RBSH;

    // weight prep
    wprep_k<<<(C * GH + 255) / 256, 256, 0, stream>>>(Wg1, wt_g1, C, GH, C, 0);
    wprep_k<<<(GH * GH + 255) / 256, 256, 0, stream>>>(Wrel, wt_rr, GH, GH, 512, 0);
    wprep_k<<<(GH * GH + 255) / 256, 256, 0, stream>>>(Wroot, wt_rr, GH, GH, 512, GH);
    wprep_k<<<(GH * C + 255) / 256, 256, 0, stream>>>(Wg2, wt_g2, GH, C, GH, 0);
    wprep_k<<<(C * FH + 255) / 256, 256, 0, stream>>>(Wf1, wt_f1, C, FH, C, 0);
    wprep_k<<<(FH * C + 255) / 256, 256, 0, stream>>>(Wf2, wt_f2, FH, C, FH, 0);

    const int nstats = 2 * (GH + C + FH + C);
    zero_k<<<(nstats + 255) / 256, 256, 0, stream>>>((int*)stats, nstats);
    zero_k<<<(256 * 16 + 255) / 256, 256, 0, stream>>>(bcnt, 256 * 16);

    // bucketed CSR build
    bhist_k<<<1024, 256, 0, stream>>>(e_dst, bcnt, E);
    bscan_k<<<1, 256, 0, stream>>>(bcnt, bbase, bcur, nbuk, E);
    bpart_k<<<(E + PCH - 1) / PCH, 512, 0, stream>>>(e_src, e_dst, bcur, pairs, E);
    bbuild_k<<<nbuk, 1024, 0, stream>>>(pairs, bbase, offsets, esrc, N, E);

    // x -> bf16 (buf0 overlay, pairs dead)
    xcast_k<<<(int)(((size_t)N * C / 8 + 255) / 256), 256, 0, stream>>>(x, x_bf, (long)N * C / 8);

    // ---- Grapher ----
    // h1raw = x @ Wg1 + bg1 -> AG[:,256:512] (stride 512)
    gemm3_k<192, false, false><<<GB * (GH / 64), 256, 0, stream>>>(
        x_bf, wt_g1, bg1, AG, N, GH / 64, 512, 256, nullptr, nullptr);
    // stats of h1raw (strided read)
    colstats_k<256><<<512, 256, 0, stream>>>(AG, sum1, sq1, N, 512, 256);
    // BN1 folding
    mkbn_k<<<1, 256, 0, stream>>>(sum1, sq1, gg1, beg1, brel, scv, shv, bias2, rvec, GH, invN);
    wscale_k<<<(GH * 512 + 255) / 256, 256, 0, stream>>>(wt_rr, scv, GH * 512);
    biasrr_k<<<8, 256, 0, stream>>>(Wrel, Wroot, shv, bias2, rvec);
    // agg(raw h1) -> AG[:,0:256]
    agg_k<<<(N + 3) / 4, 256, 0, stream>>>(AG + 256, offsets, esrc, AG, N);
    // g = gelu([agg|h1raw] @ sc-scaled [Wrel;Wroot] + bias2 + deg*rvec)
    gemm3_k<512, true, true><<<GB * (GH / 64), 256, 0, stream>>>(
        AG, wt_rr, bias2, g, N, GH / 64, GH, 0, offsets, rvec);
    // h2 = g @ Wg2 + bg2
    gemm3_k<256, false, false><<<GB * (C / 64), 256, 0, stream>>>(
        g, wt_g2, bg2, h2, N, C / 64, C, 0, nullptr, nullptr);
    colstats_k<192><<<512, 192, 0, stream>>>(h2, sum2, sq2, N, 192, 0);
    // x2 = BN(h2) + x   (in-place)
    bn_apply_k<192, false, true, true, false><<<(int)(((size_t)N * C / 8 + 255) / 256), 256, 0, stream>>>(
        h2, h2, x, sum2, sq2, gg2, beg2, N, 192, 0, invN);

    // ---- FFN ----
    // f1 = x2 @ Wf1 + bf1
    gemm3_k<192, false, false><<<GB * (FH / 64), 256, 0, stream>>>(
        h2, wt_f1, bf1, f1, N, FH / 64, FH, 0, nullptr, nullptr);
    colstats_k<512><<<512, 256, 0, stream>>>(f1, sum3, sq3, N, 512, 0);
    // g2 = gelu(BN(f1))  (in-place)
    bn_apply_k<512, true, false, false, false><<<(int)(((size_t)N * FH / 8 + 255) / 256), 256, 0, stream>>>(
        f1, f1, nullptr, sum3, sq3, gf1, bef1, N, 512, 0, invN);
    // h4 = g2 @ Wf2 + bf2
    gemm3_k<512, false, false><<<GB * (C / 64), 256, 0, stream>>>(
        f1, wt_f2, bf2, h4, N, C / 64, C, 0, nullptr, nullptr);
    colstats_k<192><<<512, 192, 0, stream>>>(h4, sum4, sq4, N, 192, 0);
    // out = BN(h4) + x2  (fp32 out)
    bn_apply_k<192, false, true, false, true><<<(int)(((size_t)N * C / 8 + 255) / 256), 256, 0, stream>>>(
        h4, d_out, h2, sum4, sq4, gf2, bef2, N, 192, 0, invN);
}

// Round 10
// 768.764 us; speedup vs baseline: 1.0520x; 1.0520x over previous
//
#include <hip/hip_runtime.h>
#include <math.h>

// ---------------- types ----------------
typedef __bf16 bf16x8 __attribute__((ext_vector_type(8)));
typedef float  floatx4 __attribute__((ext_vector_type(4)));

__device__ inline float bf_lo(unsigned u){ return __uint_as_float(u << 16); }
__device__ inline float bf_hi(unsigned u){ return __uint_as_float(u & 0xffff0000u); }
__device__ inline unsigned short f2bf_u(float f){
    unsigned u = __float_as_uint(f);
    return (unsigned short)((u + 0x7fffu + ((u >> 16) & 1u)) >> 16);   // RNE
}
__device__ inline unsigned pack2(float a, float b){
    return (unsigned)f2bf_u(a) | ((unsigned)f2bf_u(b) << 16);
}
__device__ inline float gelu_f(float v){
    return 0.5f * v * (1.f + erff(v * 0.70710678118654752f));
}
__device__ inline void gload_lds16(const void* g, void* l){
    __builtin_amdgcn_global_load_lds(
        (const __attribute__((address_space(1))) unsigned int*)g,
        (__attribute__((address_space(3))) unsigned int*)l, 16, 0, 0);
}

// ---------------- utility ----------------
__global__ void zero_k(int* __restrict__ p, int n){
    int i = blockIdx.x * 256 + threadIdx.x;
    if (i < n) p[i] = 0;
}

__global__ void xcast_k(const float* __restrict__ x, unsigned short* __restrict__ xb, long n8){
    long i = (long)blockIdx.x * 256 + threadIdx.x;
    if (i < n8){
        const float4* p = (const float4*)(x + i * 8);
        float4 a = p[0], b = p[1];
        uint4 o;
        o.x = pack2(a.x, a.y); o.y = pack2(a.z, a.w);
        o.z = pack2(b.x, b.y); o.w = pack2(b.z, b.w);
        *(uint4*)(xb + i * 8) = o;
    }
}

// Wt[n*ostride + ooffs + k] = W[k][n], bf16
__global__ void wprep_k(const float* __restrict__ W, unsigned short* __restrict__ Wt,
                        int K, int Ncols, int ostride, int ooffs){
    int idx = blockIdx.x * 256 + threadIdx.x;
    if (idx < K * Ncols){
        int k = idx / Ncols, n = idx - k * Ncols;
        Wt[(size_t)n * ostride + ooffs + k] = f2bf_u(W[idx]);
    }
}

// ---------------- BN1 folding helpers ----------------
__global__ void mkbn_k(const float* __restrict__ gsum, const float* __restrict__ gsq,
                       const float* __restrict__ gamma, const float* __restrict__ beta,
                       const float* __restrict__ brel,
                       float* __restrict__ scv, float* __restrict__ shv,
                       float* __restrict__ bias2, float* __restrict__ rvec,
                       int C_, float invN){
    int c = blockIdx.x * 256 + threadIdx.x;
    if (c < C_){
        float mean = gsum[c] * invN;
        float var  = gsq[c] * invN - mean * mean;
        float sc   = gamma[c] * rsqrtf(var + 1e-5f);
        scv[c] = sc;
        shv[c] = beta[c] - mean * sc;
        bias2[c] = brel[c];
        rvec[c]  = 0.f;
    }
}

// wt_rr[n][k'] *= sc[k' & 255]
__global__ void wscale_k(unsigned short* __restrict__ wt, const float* __restrict__ scv, int total){
    int i = blockIdx.x * 256 + threadIdx.x;
    if (i < total){
        float v = __uint_as_float(((unsigned)wt[i]) << 16);
        wt[i] = f2bf_u(v * scv[i & 255]);
    }
}

// bias2[m] += sh@Wroot[:,m];  rvec[m] += sh@Wrel[:,m]  (8 blocks, k-split)
__global__ void biasrr_k(const float* __restrict__ Wrel, const float* __restrict__ Wroot,
                         const float* __restrict__ shv,
                         float* __restrict__ bias2, float* __restrict__ rvec){
    int m = threadIdx.x;
    int k0 = blockIdx.x * 32;
    float b2 = 0.f, rv = 0.f;
    for (int k = k0; k < k0 + 32; ++k){
        float s = shv[k];
        rv = fmaf(s, Wrel[k * 256 + m], rv);
        b2 = fmaf(s, Wroot[k * 256 + m], b2);
    }
    atomicAdd(&bias2[m], b2);
    atomicAdd(&rvec[m],  rv);
}

// ---------------- bucketed CSR build ----------------
#define RBSH 9
#define RB   512
#define PCH  8192

__global__ __launch_bounds__(256)
void bhist_k(const int* __restrict__ dst, int* __restrict__ bcnt, int E){
    __shared__ int h[256];
    for (int i = threadIdx.x; i < 256; i += 256) h[i] = 0;
    __syncthreads();
    for (long i = (long)blockIdx.x * 256 + threadIdx.x; i < E; i += (long)gridDim.x * 256)
        atomicAdd(&h[dst[i] >> RBSH], 1);
    __syncthreads();
    int v = h[threadIdx.x];
    if (v) atomicAdd(&bcnt[threadIdx.x * 16], v);
}

__global__ void bscan_k(const int* __restrict__ bcnt, int* __restrict__ bbase,
                        int* __restrict__ bcur, int nbuk, int E){
    __shared__ int s[256];
    const int t = threadIdx.x;
    int v = (t < nbuk) ? bcnt[t * 16] : 0;
    s[t] = v; __syncthreads();
    for (int d = 1; d < 256; d <<= 1){
        int tt = (t >= d) ? s[t - d] : 0;
        __syncthreads();
        s[t] += tt;
        __syncthreads();
    }
    int excl = s[t] - v;
    if (t < nbuk){ bbase[t] = excl; bcur[t * 16] = excl; }
    if (t == 0) bbase[nbuk] = E;
}

__global__ __launch_bounds__(512)
void bpart_k(const int* __restrict__ src, const int* __restrict__ dst,
             int* __restrict__ bcur, int2* __restrict__ pairs, int E){
    __shared__ int h[256];
    __shared__ int s[256];
    __shared__ int cur[256];
    const int t = threadIdx.x;
    const int base = blockIdx.x * PCH;
    const int cnt = min(PCH, E - base);
    if (t < 256) h[t] = 0;
    __syncthreads();
    for (int i = t; i < cnt; i += 512)
        atomicAdd(&h[dst[base + i] >> RBSH], 1);
    __syncthreads();
    if (t < 256) s[t] = h[t];
    __syncthreads();
    for (int d = 1; d < 256; d <<= 1){
        int tt = 0;
        if (t < 256 && t >= d) tt = s[t - d];
        __syncthreads();
        if (t < 256) s[t] += tt;
        __syncthreads();
    }
    if (t < 256){
        int myc = h[t];
        int g = 0;
        if (myc) g = atomicAdd(&bcur[t * 16], myc);
        cur[t] = g;
    }
    __syncthreads();
    for (int i = t; i < cnt; i += 512){
        int d = dst[base + i];
        int b = d >> RBSH;
        int r = atomicAdd(&cur[b], 1);
        pairs[r] = make_int2(src[base + i], d);
    }
}

__global__ __launch_bounds__(1024)
void bbuild_k(const int2* __restrict__ pairs, const int* __restrict__ bbase,
              int* __restrict__ offsets, int* __restrict__ esrc, int N, int E){
    __shared__ int h[RB];
    __shared__ int s[RB];
    const int b = blockIdx.x;
    const int t = threadIdx.x;
    const int p0 = bbase[b], p1 = bbase[b + 1];
    if (t < RB) h[t] = 0;
    __syncthreads();
    for (int i = p0 + t; i < p1; i += 1024)
        atomicAdd(&h[pairs[i].y & (RB - 1)], 1);
    __syncthreads();
    int v = 0;
    if (t < RB){ v = h[t]; s[t] = v; }
    __syncthreads();
    for (int d = 1; d < RB; d <<= 1){
        int tt = 0;
        if (t < RB && t >= d) tt = s[t - d];
        __syncthreads();
        if (t < RB) s[t] += tt;
        __syncthreads();
    }
    if (t < RB){
        int node = (b << RBSH) + t;
        int excl = p0 + s[t] - v;
        if (node < N) offsets[node] = excl;
        h[t] = excl;
    }
    __syncthreads();
    for (int i = p0 + t; i < p1; i += 1024){
        int2 pr = pairs[i];
        int r = atomicAdd(&h[pr.y & (RB - 1)], 1);
        esrc[r] = pr.x;
    }
    if (b == 0 && t == 0) offsets[N] = E;
}

// ---------------- aggregation: agg(raw h1) into AG[:,0:256]; h1raw = AG+256, stride 512 ----------------
__global__ __launch_bounds__(256)
void agg_k(const unsigned short* __restrict__ hbn, const int* __restrict__ offsets,
           const int* __restrict__ esrc, unsigned short* __restrict__ aggout, int N){
    const int lane = threadIdx.x & 63;
    const int node = blockIdx.x * 4 + (threadIdx.x >> 6);
    if (node >= N) return;
    const int off  = offsets[node];
    const int end  = offsets[node + 1];
    const int half = lane >> 5;
    const int l32  = lane & 31;
    float a[8];
#pragma unroll
    for (int j = 0; j < 8; ++j) a[j] = 0.f;
    const unsigned short* hb = hbn + l32 * 8;
    for (int c = off; c < end; c += 64){
        const int e = c + lane;
        int sl = (e < end) ? esrc[e] : 0;
        const int cnt = min(64, end - c);
        for (int j = 0; j < cnt; j += 16){
            int   s[8];
            float m[8];
            uint4 u[8];
#pragma unroll
            for (int k = 0; k < 8; ++k){
                const int idx = j + 2 * k + half;
                s[k] = __shfl(sl, idx);
                m[k] = (idx < cnt) ? 1.f : 0.f;
            }
#pragma unroll
            for (int k = 0; k < 8; ++k)
                u[k] = *(const uint4*)(hb + (size_t)s[k] * 512);
#pragma unroll
            for (int k = 0; k < 8; ++k){
                a[0] = fmaf(m[k], bf_lo(u[k].x), a[0]);
                a[1] = fmaf(m[k], bf_hi(u[k].x), a[1]);
                a[2] = fmaf(m[k], bf_lo(u[k].y), a[2]);
                a[3] = fmaf(m[k], bf_hi(u[k].y), a[3]);
                a[4] = fmaf(m[k], bf_lo(u[k].z), a[4]);
                a[5] = fmaf(m[k], bf_hi(u[k].z), a[5]);
                a[6] = fmaf(m[k], bf_lo(u[k].w), a[6]);
                a[7] = fmaf(m[k], bf_hi(u[k].w), a[7]);
            }
        }
    }
#pragma unroll
    for (int j = 0; j < 8; ++j)
        a[j] += __shfl_xor(a[j], 32);
    if (half == 0){
        uint4 o;
        o.x = pack2(a[0], a[1]); o.y = pack2(a[2], a[3]);
        o.z = pack2(a[4], a[5]); o.w = pack2(a[6], a[7]);
        *(uint4*)(aggout + (size_t)node * 512 + l32 * 8) = o;
    }
}

// ---------------- GEMM (R8 single-buffer + XCD-chunked grid + deg rank-1 + scratch stats) ----------------
// STATS: per-block 64-col partial sum/sumsq -> psum/psq[xb*(NY*64)+col]
// (coalesced store, NO atomics; colreduce_k finishes).
template<int K, bool GELU_OUT, bool DEGBIAS, bool STATS>
__global__ __launch_bounds__(256)
void gemm3_k(const unsigned short* __restrict__ A, const unsigned short* __restrict__ Bt,
             const float* __restrict__ bias, unsigned short* __restrict__ Cp,
             long M, int NY, int ostride, int ooffs,
             const int* __restrict__ offs, const float* __restrict__ rvec,
             float* __restrict__ psum, float* __restrict__ psq){
    __shared__ unsigned short Xs[128 * 64];   // [row][k]
    __shared__ unsigned short Ws[64 * 64];    // [col][k]
    const int t    = threadIdx.x;
    const int lane = t & 63;
    const int w    = t >> 6;
    const int r16  = lane & 15;
    const int q4   = lane >> 4;

    // bijective XCD remap + y-fastest decomposition
    const int nwg  = gridDim.x;
    const int orig = blockIdx.x;
    const int qq   = nwg >> 3, rr = nwg & 7;
    const int xcd  = orig & 7, kk = orig >> 3;
    const int wgid = (xcd < rr ? xcd * (qq + 1) : rr * (qq + 1) + (xcd - rr) * qq) + kk;
    const int xb   = wgid / NY;
    const int yb   = wgid - xb * NY;
    const long mbase = (long)xb * 128;
    const int  cb    = yb * 64;

    floatx4 acc[4][2];
#pragma unroll
    for (int ai = 0; ai < 4; ++ai)
#pragma unroll
        for (int bi = 0; bi < 2; ++bi) acc[ai][bi] = (floatx4)0.f;

    const int lrow = w * 8 + (lane >> 3);
    const int lk   = (lane & 7) * 8;
    const unsigned short* ga = A  + (size_t)(mbase + lrow) * K + lk;
    const unsigned short* gb = Bt + (size_t)(cb + lrow) * K + lk;
    unsigned short* lx = Xs + w * 512 + lane * 8;
    unsigned short* lw = Ws + w * 512 + lane * 8;

    for (int kt = 0; kt < K; kt += 64){
#pragma unroll
        for (int i = 0; i < 4; ++i)
            gload_lds16(ga + (size_t)i * 32 * K + kt, lx + i * 2048);
#pragma unroll
        for (int j = 0; j < 2; ++j)
            gload_lds16(gb + (size_t)j * 32 * K + kt, lw + j * 2048);
        asm volatile("s_waitcnt vmcnt(0)" ::: "memory");
        __syncthreads();
#pragma unroll
        for (int kc = 0; kc < 64; kc += 32){
            bf16x8 wf[4], xf[2];
#pragma unroll
            for (int ai = 0; ai < 4; ++ai)
                wf[ai] = *(const bf16x8*)(Ws + (ai * 16 + r16) * 64 + kc + q4 * 8);
#pragma unroll
            for (int bi = 0; bi < 2; ++bi)
                xf[bi] = *(const bf16x8*)(Xs + (w * 32 + bi * 16 + r16) * 64 + kc + q4 * 8);
#pragma unroll
            for (int ai = 0; ai < 4; ++ai)
#pragma unroll
                for (int bi = 0; bi < 2; ++bi)
                    acc[ai][bi] = __builtin_amdgcn_mfma_f32_16x16x32_bf16(
                        wf[ai], xf[bi], acc[ai][bi], 0, 0, 0);
        }
        __syncthreads();
    }

    float4 bv[4];
#pragma unroll
    for (int ai = 0; ai < 4; ++ai)
        bv[ai] = *(const float4*)(bias + cb + ai * 16 + q4 * 4);
    float4 rv[4];
    if constexpr (DEGBIAS){
#pragma unroll
        for (int ai = 0; ai < 4; ++ai)
            rv[ai] = *(const float4*)(rvec + cb + ai * 16 + q4 * 4);
    }
    float cs[4][4], cq[4][4];
    if constexpr (STATS){
#pragma unroll
        for (int ai = 0; ai < 4; ++ai)
#pragma unroll
            for (int j = 0; j < 4; ++j){ cs[ai][j] = 0.f; cq[ai][j] = 0.f; }
    }
#pragma unroll
    for (int bi = 0; bi < 2; ++bi){
        long node = mbase + w * 32 + bi * 16 + r16;
        const bool valid = node < M;
        float degf = 0.f;
        if constexpr (DEGBIAS){
            if (valid) degf = (float)(offs[node + 1] - offs[node]);
        }
        unsigned short* cp = Cp + (size_t)node * ostride + ooffs + cb;
#pragma unroll
        for (int ai = 0; ai < 4; ++ai){
            float v0 = acc[ai][bi][0] + bv[ai].x;
            float v1 = acc[ai][bi][1] + bv[ai].y;
            float v2 = acc[ai][bi][2] + bv[ai].z;
            float v3 = acc[ai][bi][3] + bv[ai].w;
            if constexpr (DEGBIAS){
                v0 = fmaf(degf, rv[ai].x, v0);
                v1 = fmaf(degf, rv[ai].y, v1);
                v2 = fmaf(degf, rv[ai].z, v2);
                v3 = fmaf(degf, rv[ai].w, v3);
            }
            if constexpr (STATS){
                float mm = valid ? 1.f : 0.f;
                cs[ai][0] += mm * v0; cq[ai][0] = fmaf(mm * v0, v0, cq[ai][0]);
                cs[ai][1] += mm * v1; cq[ai][1] = fmaf(mm * v1, v1, cq[ai][1]);
                cs[ai][2] += mm * v2; cq[ai][2] = fmaf(mm * v2, v2, cq[ai][2]);
                cs[ai][3] += mm * v3; cq[ai][3] = fmaf(mm * v3, v3, cq[ai][3]);
            }
            if constexpr (GELU_OUT){
                v0 = gelu_f(v0); v1 = gelu_f(v1); v2 = gelu_f(v2); v3 = gelu_f(v3);
            }
            if (valid){
                uint2 o; o.x = pack2(v0, v1); o.y = pack2(v2, v3);
                *(uint2*)(cp + ai * 16 + q4 * 4) = o;
            }
        }
    }

    if constexpr (STATS){
        // reduce over the 16 node-lanes (r16) via xor-shuffles
#pragma unroll
        for (int ai = 0; ai < 4; ++ai)
#pragma unroll
            for (int j = 0; j < 4; ++j){
#pragma unroll
                for (int m = 1; m < 16; m <<= 1){
                    cs[ai][j] += __shfl_xor(cs[ai][j], m);
                    cq[ai][j] += __shfl_xor(cq[ai][j], m);
                }
            }
        float* ssum = (float*)Xs;          // [4 waves][64 cols]
        float* ssq  = ssum + 256;
        if (r16 == 0){
#pragma unroll
            for (int ai = 0; ai < 4; ++ai)
#pragma unroll
                for (int j = 0; j < 4; ++j){
                    ssum[w * 64 + ai * 16 + q4 * 4 + j] = cs[ai][j];
                    ssq [w * 64 + ai * 16 + q4 * 4 + j] = cq[ai][j];
                }
        }
        __syncthreads();
        if (t < 64){
            float s = 0.f, q = 0.f;
#pragma unroll
            for (int ww = 0; ww < 4; ++ww){ s += ssum[ww * 64 + t]; q += ssq[ww * 64 + t]; }
            const int nc = NY * 64;
            psum[(size_t)xb * nc + cb + t] = s;   // coalesced, no atomics
            psq [(size_t)xb * nc + cb + t] = q;
        }
    }
}

// ---------------- finish stats: gsum[c] = sum_xb psum[xb][c] ----------------
__global__ void colreduce_k(const float* __restrict__ ps, const float* __restrict__ pq,
                            float* __restrict__ gsum, float* __restrict__ gsq,
                            int ncols, int nxb){
    __shared__ float ss[256], sq_[256];
    const int c = blockIdx.x;
    float s = 0.f, q = 0.f;
    for (int i = threadIdx.x; i < nxb; i += 256){
        s += ps[(size_t)i * ncols + c];
        q += pq[(size_t)i * ncols + c];
    }
    ss[threadIdx.x] = s; sq_[threadIdx.x] = q;
    __syncthreads();
    for (int d = 128; d > 0; d >>= 1){
        if (threadIdx.x < d){
            ss[threadIdx.x]  += ss[threadIdx.x + d];
            sq_[threadIdx.x] += sq_[threadIdx.x + d];
        }
        __syncthreads();
    }
    if (threadIdx.x == 0){ gsum[c] = ss[0]; gsq[c] = sq_[0]; }
}

// ---------------- BN apply (+gelu, +residual, strided out, fp32/bf16 out) ----------------
template<int NCOLS, bool GELU_OUT, bool RES, bool RES_F32, bool OUT_F32>
__global__ __launch_bounds__(256)
void bn_apply_k(const unsigned short* __restrict__ in, void* __restrict__ outv,
                const void* __restrict__ resv,
                const float* __restrict__ gsum, const float* __restrict__ gsq,
                const float* __restrict__ gamma, const float* __restrict__ beta,
                long nrows, int ostride, int ooffs, float invN){
    __shared__ float s_scale[NCOLS], s_shift[NCOLS];
    for (int c = threadIdx.x; c < NCOLS; c += 256){
        float mean = gsum[c] * invN;
        float var  = gsq[c] * invN - mean * mean;
        float sc   = gamma[c] * rsqrtf(var + 1e-5f);
        s_scale[c] = sc;
        s_shift[c] = beta[c] - mean * sc;
    }
    __syncthreads();
    long i8 = ((long)blockIdx.x * 256 + threadIdx.x) * 8;
    if (i8 >= nrows * (long)NCOLS) return;
    long row  = i8 / NCOLS;
    int  col0 = (int)(i8 - row * NCOLS);
    uint4 u = *(const uint4*)(in + i8);
    float v[8];
    v[0] = bf_lo(u.x); v[1] = bf_hi(u.x); v[2] = bf_lo(u.y); v[3] = bf_hi(u.y);
    v[4] = bf_lo(u.z); v[5] = bf_hi(u.z); v[6] = bf_lo(u.w); v[7] = bf_hi(u.w);
#pragma unroll
    for (int j = 0; j < 8; ++j){
        v[j] = v[j] * s_scale[col0 + j] + s_shift[col0 + j];
        if constexpr (GELU_OUT) v[j] = gelu_f(v[j]);
    }
    if constexpr (RES){
        if constexpr (RES_F32){
            const float4* rp = (const float4*)((const float*)resv + i8);
            float4 r0 = rp[0], r1 = rp[1];
            v[0] += r0.x; v[1] += r0.y; v[2] += r0.z; v[3] += r0.w;
            v[4] += r1.x; v[5] += r1.y; v[6] += r1.z; v[7] += r1.w;
        } else {
            uint4 r = *(const uint4*)((const unsigned short*)resv + i8);
            v[0] += bf_lo(r.x); v[1] += bf_hi(r.x); v[2] += bf_lo(r.y); v[3] += bf_hi(r.y);
            v[4] += bf_lo(r.z); v[5] += bf_hi(r.z); v[6] += bf_lo(r.w); v[7] += bf_hi(r.w);
        }
    }
    long opos = row * ostride + ooffs + col0;
    if constexpr (OUT_F32){
        float4* op = (float4*)((float*)outv + opos);
        op[0] = make_float4(v[0], v[1], v[2], v[3]);
        op[1] = make_float4(v[4], v[5], v[6], v[7]);
    } else {
        uint4 o;
        o.x = pack2(v[0], v[1]); o.y = pack2(v[2], v[3]);
        o.z = pack2(v[4], v[5]); o.w = pack2(v[6], v[7]);
        *(uint4*)((unsigned short*)outv + opos) = o;
    }
}

// ---------------- host ----------------
extern "C" void kernel_launch(void* const* d_in, const int* in_sizes, int n_in,
                              void* d_out, int out_size, void* d_ws, size_t ws_size,
                              hipStream_t stream){
    const int C = 192, GH = 256, FH = 512;
    const float* x    = (const float*)d_in[0];
    const int*   ei   = (const int*)d_in[1];
    const float* Wg1  = (const float*)d_in[2];
    const float* bg1  = (const float*)d_in[3];
    const float* gg1  = (const float*)d_in[4];
    const float* beg1 = (const float*)d_in[5];
    const float* Wrel = (const float*)d_in[6];
    const float* brel = (const float*)d_in[7];
    const float* Wroot= (const float*)d_in[8];
    const float* Wg2  = (const float*)d_in[9];
    const float* bg2  = (const float*)d_in[10];
    const float* gg2  = (const float*)d_in[11];
    const float* beg2 = (const float*)d_in[12];
    const float* Wf1  = (const float*)d_in[13];
    const float* bf1  = (const float*)d_in[14];
    const float* gf1  = (const float*)d_in[15];
    const float* bef1 = (const float*)d_in[16];
    const float* Wf2  = (const float*)d_in[17];
    const float* bf2  = (const float*)d_in[18];
    const float* gf2  = (const float*)d_in[19];
    const float* bef2 = (const float*)d_in[20];

    const int N = in_sizes[0] / C;
    const int E = in_sizes[1] / 2;
    const int* e_src = ei;
    const int* e_dst = ei + E;

    char* wp = (char*)d_ws;
    auto carve = [&](size_t bytes) -> void* {
        void* p = (void*)wp; wp += (bytes + 255) & ~(size_t)255; return p;
    };
    unsigned short* wt_g1 = (unsigned short*)carve((size_t)GH * C * 2);
    unsigned short* wt_rr = (unsigned short*)carve((size_t)GH * 512 * 2);
    unsigned short* wt_g2 = (unsigned short*)carve((size_t)C * GH * 2);
    unsigned short* wt_f1 = (unsigned short*)carve((size_t)FH * C * 2);
    unsigned short* wt_f2 = (unsigned short*)carve((size_t)C * FH * 2);
    float* stats = (float*)carve(2 * (size_t)(GH + C + FH + C) * 4);
    float* sum1 = stats;        float* sq1 = sum1 + GH;
    float* sum2 = sq1 + GH;     float* sq2 = sum2 + C;
    float* sum3 = sq2 + C;      float* sq3 = sum3 + FH;
    float* sum4 = sq3 + FH;     float* sq4 = sum4 + C;
    float* scv   = (float*)carve(256 * 4);
    float* shv   = (float*)carve(256 * 4);
    float* bias2 = (float*)carve(256 * 4);
    float* rvec  = (float*)carve(256 * 4);
    const int GB = (N + 127) / 128;
    float* psum = (float*)carve((size_t)GB * 512 * 4);   // per-xb stats scratch
    float* psq  = (float*)carve((size_t)GB * 512 * 4);
    // buf0: pairs (build) -> x_bf[N,192] -> g[N,256] -> f1/g2[N,512]
    unsigned short* buf0  = (unsigned short*)carve((size_t)N * 512 * 2);
    // bufAG: AG=[agg|h1raw] stride 512 -> h2/x2[N,192]@0, h4[N,192]@N*192
    unsigned short* bufAG = (unsigned short*)carve((size_t)N * 512 * 2);
    int* offsets = (int*)carve((size_t)(N + 1) * 4);
    int* esrc    = (int*)carve((size_t)E * 4);
    int* bcnt    = (int*)carve((size_t)256 * 16 * 4);
    int* bbase   = (int*)carve((size_t)257 * 4);
    int* bcur    = (int*)carve((size_t)256 * 16 * 4);
    int2* pairs = (int2*)buf0;
    unsigned short* x_bf = buf0;
    unsigned short* g    = buf0;
    unsigned short* f1   = buf0;
    unsigned short* AG   = bufAG;
    unsigned short* h2   = bufAG;
    unsigned short* h4   = bufAG + (size_t)N * C;
    (void)ws_size; (void)n_in; (void)out_size;

    const float invN = 1.0f / (float)N;
    const int nbuk = (N + RB - 1) >> RBSH;

    // weight prep
    wprep_k<<<(C * GH + 255) / 256, 256, 0, stream>>>(Wg1, wt_g1, C, GH, C, 0);
    wprep_k<<<(GH * GH + 255) / 256, 256, 0, stream>>>(Wrel, wt_rr, GH, GH, 512, 0);
    wprep_k<<<(GH * GH + 255) / 256, 256, 0, stream>>>(Wroot, wt_rr, GH, GH, 512, GH);
    wprep_k<<<(GH * C + 255) / 256, 256, 0, stream>>>(Wg2, wt_g2, GH, C, GH, 0);
    wprep_k<<<(C * FH + 255) / 256, 256, 0, stream>>>(Wf1, wt_f1, C, FH, C, 0);
    wprep_k<<<(FH * C + 255) / 256, 256, 0, stream>>>(Wf2, wt_f2, FH, C, FH, 0);

    zero_k<<<(256 * 16 + 255) / 256, 256, 0, stream>>>(bcnt, 256 * 16);

    // bucketed CSR build
    bhist_k<<<1024, 256, 0, stream>>>(e_dst, bcnt, E);
    bscan_k<<<1, 256, 0, stream>>>(bcnt, bbase, bcur, nbuk, E);
    bpart_k<<<(E + PCH - 1) / PCH, 512, 0, stream>>>(e_src, e_dst, bcur, pairs, E);
    bbuild_k<<<nbuk, 1024, 0, stream>>>(pairs, bbase, offsets, esrc, N, E);

    // x -> bf16 (buf0 overlay, pairs dead)
    xcast_k<<<(int)(((size_t)N * C / 8 + 255) / 256), 256, 0, stream>>>(x, x_bf, (long)N * C / 8);

    // ---- Grapher ----
    // h1raw = x @ Wg1 + bg1 -> AG[:,256:512]; fused scratch-stats
    gemm3_k<192, false, false, true><<<GB * (GH / 64), 256, 0, stream>>>(
        x_bf, wt_g1, bg1, AG, N, GH / 64, 512, 256, nullptr, nullptr, psum, psq);
    colreduce_k<<<GH, 256, 0, stream>>>(psum, psq, sum1, sq1, GH, GB);
    // BN1 folding
    mkbn_k<<<1, 256, 0, stream>>>(sum1, sq1, gg1, beg1, brel, scv, shv, bias2, rvec, GH, invN);
    wscale_k<<<(GH * 512 + 255) / 256, 256, 0, stream>>>(wt_rr, scv, GH * 512);
    biasrr_k<<<8, 256, 0, stream>>>(Wrel, Wroot, shv, bias2, rvec);
    // agg(raw h1) -> AG[:,0:256]
    agg_k<<<(N + 3) / 4, 256, 0, stream>>>(AG + 256, offsets, esrc, AG, N);
    // g = gelu([agg|h1raw] @ sc-scaled [Wrel;Wroot] + bias2 + deg*rvec)
    gemm3_k<512, true, true, false><<<GB * (GH / 64), 256, 0, stream>>>(
        AG, wt_rr, bias2, g, N, GH / 64, GH, 0, offsets, rvec, nullptr, nullptr);
    // h2 = g @ Wg2 + bg2; fused scratch-stats
    gemm3_k<256, false, false, true><<<GB * (C / 64), 256, 0, stream>>>(
        g, wt_g2, bg2, h2, N, C / 64, C, 0, nullptr, nullptr, psum, psq);
    colreduce_k<<<C, 256, 0, stream>>>(psum, psq, sum2, sq2, C, GB);
    // x2 = BN(h2) + x   (in-place)
    bn_apply_k<192, false, true, true, false><<<(int)(((size_t)N * C / 8 + 255) / 256), 256, 0, stream>>>(
        h2, h2, x, sum2, sq2, gg2, beg2, N, 192, 0, invN);

    // ---- FFN ----
    // f1 = x2 @ Wf1 + bf1; fused scratch-stats
    gemm3_k<192, false, false, true><<<GB * (FH / 64), 256, 0, stream>>>(
        h2, wt_f1, bf1, f1, N, FH / 64, FH, 0, nullptr, nullptr, psum, psq);
    colreduce_k<<<FH, 256, 0, stream>>>(psum, psq, sum3, sq3, FH, GB);
    // g2 = gelu(BN(f1))  (in-place)
    bn_apply_k<512, true, false, false, false><<<(int)(((size_t)N * FH / 8 + 255) / 256), 256, 0, stream>>>(
        f1, f1, nullptr, sum3, sq3, gf1, bef1, N, 512, 0, invN);
    // h4 = g2 @ Wf2 + bf2; fused scratch-stats
    gemm3_k<512, false, false, true><<<GB * (C / 64), 256, 0, stream>>>(
        f1, wt_f2, bf2, h4, N, C / 64, C, 0, nullptr, nullptr, psum, psq);
    colreduce_k<<<C, 256, 0, stream>>>(psum, psq, sum4, sq4, C, GB);
    // out = BN(h4) + x2  (fp32 out)
    bn_apply_k<192, false, true, false, true><<<(int)(((size_t)N * C / 8 + 255) / 256), 256, 0, stream>>>(
        h4, d_out, h2, sum4, sq4, gf2, bef2, N, 192, 0, invN);
}